// Round 3
// baseline (455.299 us; speedup 1.0000x reference)
//
#include <hip/hip_runtime.h>

// SelfEquiConv E=100000, S=64, V=32 — f16 MFMA formulation (round 5).
// vs r4: (a) LDS 41984 -> 40960 B (stride 320 f16 + XOR swizzle byte^=(e&7)<<4)
//            => 4 blocks/CU; __launch_bounds__(256,4).
//        (b) B-prefetch ring deepened 2 -> 4 chunks (static slot = c&3) in G1 & G2.
//        (c) s2q/v2q preloads moved into consuming phases to cap VGPR peak.

typedef _Float16 f16;
typedef _Float16 f16x8 __attribute__((ext_vector_type(8)));
typedef float    f32x4 __attribute__((ext_vector_type(4)));

constexpr float A_SS  = 0.011048543456039806f; // (2*64*64)^-0.5  == A_SS_G
constexpr float A_VV  = 0.012757759747374832f; // (2*32*32*3)^-0.5 == A_VV_G
constexpr float A_SV  = 0.009021097956087904f; // (2*64*32*3)^-0.5 == A_VS_V
constexpr float SO_SC = 0.125f;                // 64^-0.5
constexpr float VO_SC = 0.1767766952966369f;   // 32^-0.5

#define MFMA16(A, B, C) __builtin_amdgcn_mfma_f32_16x16x32_f16((A), (B), (C), 0, 0, 0)

static __device__ __forceinline__ f16x8 splat8(f16 x) {
    return (f16x8){x, x, x, x, x, x, x, x};
}

// ---------------- prep: swizzle weights into MFMA B-fragment order (f16) ----------------
// b1p:  [160 kchunks][6 t][64 L][8]   k=c*32+(L>>4)*8+j, n=t*16+(L&15)
// b2p:  [128 kchunks][2 t][64 L][8]
// wlsP: [2 kc][4 t][64 L][8]          *SO_SC
// wlvP: [2 t][64 L][8]                *VO_SC
__global__ void prep_weights(const float* __restrict__ wss_s, const float* __restrict__ wvv_s,
                             const float* __restrict__ wss_g, const float* __restrict__ wvv_g,
                             const float* __restrict__ wsv,   const float* __restrict__ wvs,
                             const float* __restrict__ wls,   const float* __restrict__ wlv,
                             f16* __restrict__ b1p, f16* __restrict__ b2p,
                             f16* __restrict__ wlsP, f16* __restrict__ wlvP)
{
    int idx = blockIdx.x * 256 + threadIdx.x;
    const int N1 = 160 * 6 * 512;          // 491520
    const int N2 = 128 * 2 * 512;          // 131072
    const int N3 = 8 * 512;                // 4096
    const int N4 = 2 * 512;                // 1024
    if (idx < N1) {
        int j = idx & 7, L = (idx >> 3) & 63, ct = idx >> 9;
        int t = ct % 6, c = ct / 6;
        int k = c * 32 + (L >> 4) * 8 + j;
        int n = t * 16 + (L & 15);
        float val;
        if (k < 4096) { int u = k >> 6, v = k & 63, p = u * 64 + v;
            val = A_SS * (n < 64 ? wss_s[p * 64 + n] : wss_g[p * 32 + (n - 64)]);
        } else { int k2 = k - 4096; int u = k2 >> 5, v = k2 & 31, p = u * 32 + v;
            val = A_VV * (n < 64 ? wvv_s[p * 64 + n] : wvv_g[p * 32 + (n - 64)]);
        }
        b1p[idx] = (f16)val;
    } else if (idx < N1 + N2) {
        int id2 = idx - N1;
        int j = id2 & 7, L = (id2 >> 3) & 63, ct = id2 >> 9;
        int t = ct & 1, c = ct >> 1;
        int k = c * 32 + (L >> 4) * 8 + j;
        int n = t * 16 + (L & 15);
        float val;
        if (k < 2048) { int u = k >> 5, v = k & 31; val = wsv[(u * 32 + v) * 32 + n]; }
        else { int k2 = k - 2048; int u = k2 >> 6, v = k2 & 63; val = wvs[(u * 64 + v) * 32 + n]; }
        b2p[id2] = (f16)(A_SV * val);
    } else if (idx < N1 + N2 + N3) {
        int id3 = idx - N1 - N2;
        int j = id3 & 7, L = (id3 >> 3) & 63, ct = id3 >> 9;   // ct in [0,8)
        int t = ct & 3, kc = ct >> 2;
        int k = kc * 32 + (L >> 4) * 8 + j;
        int n = t * 16 + (L & 15);
        wlsP[id3] = (f16)(SO_SC * wls[k * 64 + n]);
    } else if (idx < N1 + N2 + N3 + N4) {
        int id4 = idx - N1 - N2 - N3;
        int j = id4 & 7, L = (id4 >> 3) & 63, t = id4 >> 9;    // t in [0,2)
        int k = (L >> 4) * 8 + j;
        int n = t * 16 + (L & 15);
        wlvP[id4] = (f16)(VO_SC * wlv[k * 32 + n]);
    }
}

// ---------------- main kernel: 64 edges/block, 4 waves, 4 blocks/CU ----------------
// smem (40960 B total):
//   phase 1: IN f16 [64 rows][320], row stride 640 B (128B-aligned), XOR-swizzled:
//            byte = (e*640 + hc*2) ^ ((e&7)<<4). s1@0, s2@64, v1T@128 (i*32+v), v2T@224.
//   phase 2 (overlay): zSh f16 [64][72] @0, zGh f16 [64][34] @9216, ZVH f16 [192][40] @13568
//   phase 3: OUTV f32 [64][100] @0 (25600)
__global__ __launch_bounds__(256, 4)
void seconv_mfma(const float* __restrict__ fea1, const float* __restrict__ fea2,
                 const f16* __restrict__ b1p, const f16* __restrict__ b2p,
                 const f16* __restrict__ wlsP, const f16* __restrict__ wlvP,
                 float* __restrict__ out, int E)
{
    __shared__ __align__(128) char smem[40960];
    f16*   zSh  = (f16*)smem;             // overlays, valid after G2 barrier
    f16*   zGh  = (f16*)(smem + 9216);
    f16*   ZVH  = (f16*)(smem + 13568);
    float* OUTV = (float*)smem;

    const int tid  = threadIdx.x;
    const int lane = tid & 63;
    const int m    = lane & 15;
    const int quad = lane >> 4;
    const int w    = tid >> 6;
    const int h    = w & 1;       // G1 edge half
    const int nh   = w >> 1;      // G1 n-half (tiles 3nh..3nh+2)
    const int tb   = nh * 3;
    const int e0   = blockIdx.x * 64;

    // swizzled IN accessors (hc = f16 column index 0..319)
    auto ld8 = [&](int e, int hc) -> f16x8 {
        int b = (e * 640 + hc * 2) ^ ((e & 7) << 4);
        return *(const f16x8*)(smem + b);
    };
    auto st2 = [&](int e, int hc, f16 v) {
        int b = (e * 640 + hc * 2) ^ ((e & 7) << 4);
        *(f16*)(smem + b) = v;
    };

    // ---- stage inputs as f16 (v-parts transposed to [i][v]) ----
    for (int i = tid; i < 64 * 160; i += 256) {
        int e = i / 160, c = i - e * 160;
        int ge = e0 + e; if (ge >= E) ge = E - 1;
        float a = fea1[ge * 160 + c];
        float b = fea2[ge * 160 + c];
        if (c < 64) { st2(e, c, (f16)a); st2(e, 64 + c, (f16)b); }
        else { int c2 = c - 64; int v = c2 / 3, ii = c2 - v * 3;
               st2(e, 128 + ii * 32 + v, (f16)a);
               st2(e, 224 + ii * 32 + v, (f16)b); }
    }
    __syncthreads();

    const int eA = h * 32 + m;        // G1 strip p=0 edge
    const int eB = h * 32 + 16 + m;   // G1 strip p=1 edge

    // ================= G1: [z_s|z_g], 160 kchunks, 4-deep B ring =================
    f32x4 acc[2][3];
    #pragma unroll
    for (int p = 0; p < 2; ++p)
        #pragma unroll
        for (int t = 0; t < 3; ++t) acc[p][t] = (f32x4){0.f, 0.f, 0.f, 0.f};

    f32x4 bq[4][3];                   // slot = chunk & 3 (static after unroll)
    #pragma unroll
    for (int s = 0; s < 4; ++s)
        #pragma unroll
        for (int t = 0; t < 3; ++t)
            bq[s][t] = *(const f32x4*)(b1p + ((s * 6 + tb + t) * 64 + lane) * 8);

    // P-part: chunks 0..127, c = (ub*8+uj)*2+vh
    {
        f16x8 s2q[2][2];
        #pragma unroll
        for (int p = 0; p < 2; ++p)
            #pragma unroll
            for (int vh = 0; vh < 2; ++vh)
                s2q[p][vh] = ld8(p ? eB : eA, 64 + vh * 32 + quad * 8);

        for (int ub = 0; ub < 8; ++ub) {
            f16x8 s1Ab = ld8(eA, ub * 8);
            f16x8 s1Bb = ld8(eB, ub * 8);
            #pragma unroll
            for (int uj = 0; uj < 8; ++uj) {
                f16x8 s1A = splat8(s1Ab[uj]);
                f16x8 s1B = splat8(s1Bb[uj]);
                #pragma unroll
                for (int vh = 0; vh < 2; ++vh) {
                    const int clo = uj * 2 + vh;       // c = ub*16 + clo
                    const int slot = clo & 3;
                    f16x8 bb0 = __builtin_bit_cast(f16x8, bq[slot][0]);
                    f16x8 bb1 = __builtin_bit_cast(f16x8, bq[slot][1]);
                    f16x8 bb2 = __builtin_bit_cast(f16x8, bq[slot][2]);
                    int cn = ub * 16 + clo + 4;        // <= 131 < 160, always valid
                    #pragma unroll
                    for (int t = 0; t < 3; ++t)
                        bq[slot][t] = *(const f32x4*)(b1p + ((cn * 6 + tb + t) * 64 + lane) * 8);
                    f16x8 a0 = s1A * s2q[0][vh];
                    f16x8 a1 = s1B * s2q[1][vh];
                    acc[0][0] = MFMA16(a0, bb0, acc[0][0]);
                    acc[0][1] = MFMA16(a0, bb1, acc[0][1]);
                    acc[0][2] = MFMA16(a0, bb2, acc[0][2]);
                    acc[1][0] = MFMA16(a1, bb0, acc[1][0]);
                    acc[1][1] = MFMA16(a1, bb1, acc[1][1]);
                    acc[1][2] = MFMA16(a1, bb2, acc[1][2]);
                }
            }
        }
    }
    // Q-part: chunks 128..159, c = 128 + ub*8 + uj
    {
        f16x8 v2q[2][3];
        #pragma unroll
        for (int p = 0; p < 2; ++p)
            #pragma unroll
            for (int i3 = 0; i3 < 3; ++i3)
                v2q[p][i3] = ld8(p ? eB : eA, 224 + i3 * 32 + quad * 8);

        for (int ub = 0; ub < 4; ++ub) {
            f16x8 xA[3], xB[3];
            #pragma unroll
            for (int i3 = 0; i3 < 3; ++i3) {
                xA[i3] = ld8(eA, 128 + i3 * 32 + ub * 8);
                xB[i3] = ld8(eB, 128 + i3 * 32 + ub * 8);
            }
            #pragma unroll
            for (int uj = 0; uj < 8; ++uj) {
                const int slot = uj & 3;
                f16x8 a0 = splat8(xA[0][uj]) * v2q[0][0];
                a0 += splat8(xA[1][uj]) * v2q[0][1];
                a0 += splat8(xA[2][uj]) * v2q[0][2];
                f16x8 a1 = splat8(xB[0][uj]) * v2q[1][0];
                a1 += splat8(xB[1][uj]) * v2q[1][1];
                a1 += splat8(xB[2][uj]) * v2q[1][2];
                f16x8 bb0 = __builtin_bit_cast(f16x8, bq[slot][0]);
                f16x8 bb1 = __builtin_bit_cast(f16x8, bq[slot][1]);
                f16x8 bb2 = __builtin_bit_cast(f16x8, bq[slot][2]);
                int cn = 128 + ub * 8 + uj + 4; if (cn > 159) cn = 159;
                #pragma unroll
                for (int t = 0; t < 3; ++t)
                    bq[slot][t] = *(const f32x4*)(b1p + ((cn * 6 + tb + t) * 64 + lane) * 8);
                acc[0][0] = MFMA16(a0, bb0, acc[0][0]);
                acc[0][1] = MFMA16(a0, bb1, acc[0][1]);
                acc[0][2] = MFMA16(a0, bb2, acc[0][2]);
                acc[1][0] = MFMA16(a1, bb0, acc[1][0]);
                acc[1][1] = MFMA16(a1, bb1, acc[1][1]);
                acc[1][2] = MFMA16(a1, bb2, acc[1][2]);
            }
        }
    }

    // ================= G2: z_v, wave w owns rows (i3, e2=w*16+m), FULL K, 4-deep ring =================
    const int e2 = w * 16 + m;
    f16x8 s2g[2], v2g[3];
    #pragma unroll
    for (int vh = 0; vh < 2; ++vh)
        s2g[vh] = ld8(e2, 64 + vh * 32 + quad * 8);
    #pragma unroll
    for (int i3 = 0; i3 < 3; ++i3)
        v2g[i3] = ld8(e2, 224 + i3 * 32 + quad * 8);

    f32x4 acc2[3][2];
    #pragma unroll
    for (int i3 = 0; i3 < 3; ++i3)
        #pragma unroll
        for (int t = 0; t < 2; ++t) acc2[i3][t] = (f32x4){0.f, 0.f, 0.f, 0.f};

    f32x4 bq2[4][2];                  // slot = chunk & 3
    #pragma unroll
    for (int s = 0; s < 4; ++s)
        #pragma unroll
        for (int t = 0; t < 2; ++t)
            bq2[s][t] = *(const f32x4*)(b2p + ((s * 2 + t) * 64 + lane) * 8);

    // sv phase: chunk c = ub*8+uj: A[(i3)] = s1[e2][c] * v2T[e2][i3][quad*8+j]
    for (int ub = 0; ub < 8; ++ub) {
        f16x8 s1b = ld8(e2, ub * 8);
        #pragma unroll
        for (int uj = 0; uj < 8; ++uj) {
            const int slot = uj & 3;
            f16x8 bb0 = __builtin_bit_cast(f16x8, bq2[slot][0]);
            f16x8 bb1 = __builtin_bit_cast(f16x8, bq2[slot][1]);
            int cn = ub * 8 + uj + 4;              // <= 67 < 128, valid
            #pragma unroll
            for (int t = 0; t < 2; ++t)
                bq2[slot][t] = *(const f32x4*)(b2p + ((cn * 2 + t) * 64 + lane) * 8);
            f16x8 sxv = splat8(s1b[uj]);
            #pragma unroll
            for (int i3 = 0; i3 < 3; ++i3) {
                f16x8 a = sxv * v2g[i3];
                acc2[i3][0] = MFMA16(a, bb0, acc2[i3][0]);
                acc2[i3][1] = MFMA16(a, bb1, acc2[i3][1]);
            }
        }
    }
    // vs phase: chunk c = 64 + (ub*8+uj)*2 + vh: A[(i3)] = v1T[e2][i3][u] * s2[e2][vh*...]
    for (int ub = 0; ub < 4; ++ub) {
        f16x8 v1b[3];
        #pragma unroll
        for (int i3 = 0; i3 < 3; ++i3)
            v1b[i3] = ld8(e2, 128 + i3 * 32 + ub * 8);
        #pragma unroll
        for (int uj = 0; uj < 8; ++uj) {
            f16x8 v1s0 = splat8(v1b[0][uj]);
            f16x8 v1s1 = splat8(v1b[1][uj]);
            f16x8 v1s2 = splat8(v1b[2][uj]);
            #pragma unroll
            for (int vh = 0; vh < 2; ++vh) {
                const int slot = (uj * 2 + vh) & 3;   // (64 + ub*16) % 4 == 0
                f16x8 bb0 = __builtin_bit_cast(f16x8, bq2[slot][0]);
                f16x8 bb1 = __builtin_bit_cast(f16x8, bq2[slot][1]);
                int cn = 64 + (ub * 8 + uj) * 2 + vh + 4; if (cn > 127) cn = 127;
                #pragma unroll
                for (int t = 0; t < 2; ++t)
                    bq2[slot][t] = *(const f32x4*)(b2p + ((cn * 2 + t) * 64 + lane) * 8);
                f16x8 a0 = v1s0 * s2g[vh];
                f16x8 a1 = v1s1 * s2g[vh];
                f16x8 a2 = v1s2 * s2g[vh];
                acc2[0][0] = MFMA16(a0, bb0, acc2[0][0]);
                acc2[0][1] = MFMA16(a0, bb1, acc2[0][1]);
                acc2[1][0] = MFMA16(a1, bb0, acc2[1][0]);
                acc2[1][1] = MFMA16(a1, bb1, acc2[1][1]);
                acc2[2][0] = MFMA16(a2, bb0, acc2[2][0]);
                acc2[2][1] = MFMA16(a2, bb1, acc2[2][1]);
            }
        }
    }
    __syncthreads();   // all IN reads done — overlays become legal

    // ---- z write: silu(zS) and raw zG to LDS (overlay IN) ----
    #pragma unroll
    for (int p = 0; p < 2; ++p)
        #pragma unroll
        for (int t = 0; t < 3; ++t) {
            int n = (tb + t) * 16 + m;
            #pragma unroll
            for (int r = 0; r < 4; ++r) {
                int e_loc = h * 32 + p * 16 + quad * 4 + r;
                float z = acc[p][t][r];
                if (n < 64) {
                    float s = z / (1.f + __expf(-z));
                    zSh[e_loc * 72 + n] = (f16)s;
                } else {
                    zGh[e_loc * 34 + (n - 64)] = (f16)z;
                }
            }
        }
    __syncthreads();

    // ---- gate + ZVH write (wave w writes its own e-strip rows) ----
    #pragma unroll
    for (int t = 0; t < 2; ++t)
        #pragma unroll
        for (int r = 0; r < 4; ++r) {
            int e_loc = w * 16 + quad * 4 + r;
            float zg = (float)zGh[e_loc * 34 + t * 16 + m];
            float gate = 1.f / (1.f + __expf(-zg));
            #pragma unroll
            for (int i3 = 0; i3 < 3; ++i3)
                ZVH[(i3 * 64 + e_loc) * 40 + t * 16 + m] = (f16)(gate * acc2[i3][t][r]);
        }

    // ================= epilogue GEMMs (f16 MFMA) =================
    // GEMM-S: out_s = silu(zS) @ wlsP ; wave w owns m-strip w, 4 n-tiles
    {
        f32x4 accS[4];
        #pragma unroll
        for (int t = 0; t < 4; ++t) accS[t] = (f32x4){0.f, 0.f, 0.f, 0.f};
        #pragma unroll
        for (int kc = 0; kc < 2; ++kc) {
            f16x8 aS = *(const f16x8*)(zSh + (w * 16 + m) * 72 + kc * 32 + quad * 8);
            #pragma unroll
            for (int t = 0; t < 4; ++t) {
                f32x4 braw = *(const f32x4*)(wlsP + ((kc * 4 + t) * 64 + lane) * 8);
                accS[t] = MFMA16(aS, __builtin_bit_cast(f16x8, braw), accS[t]);
            }
        }
        #pragma unroll
        for (int t = 0; t < 4; ++t)
            #pragma unroll
            for (int r = 0; r < 4; ++r) {
                int ge = e0 + w * 16 + quad * 4 + r;
                if (ge < E) out[ge * 160 + t * 16 + m] = accS[t][r];
            }
    }
    // GEMM-V: rows (i3, e-strip w) = gated z_v @ wlvP (own-wave ZVH rows)
    {
        f32x4 accV[3][2];
        #pragma unroll
        for (int i3 = 0; i3 < 3; ++i3)
            #pragma unroll
            for (int t = 0; t < 2; ++t) accV[i3][t] = (f32x4){0.f, 0.f, 0.f, 0.f};
        f16x8 bV[2];
        #pragma unroll
        for (int t = 0; t < 2; ++t) {
            f32x4 braw = *(const f32x4*)(wlvP + (t * 64 + lane) * 8);
            bV[t] = __builtin_bit_cast(f16x8, braw);
        }
        #pragma unroll
        for (int i3 = 0; i3 < 3; ++i3) {
            f16x8 aV = *(const f16x8*)(ZVH + (i3 * 64 + w * 16 + m) * 40 + quad * 8);
            #pragma unroll
            for (int t = 0; t < 2; ++t) accV[i3][t] = MFMA16(aV, bV[t], accV[i3][t]);
        }
        __syncthreads();   // all zSh/ZVH reads done — OUTV overlay safe
        #pragma unroll
        for (int i3 = 0; i3 < 3; ++i3)
            #pragma unroll
            for (int t = 0; t < 2; ++t)
                #pragma unroll
                for (int r = 0; r < 4; ++r) {
                    int e_loc = w * 16 + quad * 4 + r;
                    OUTV[e_loc * 100 + (t * 16 + m) * 3 + i3] = accV[i3][t][r];
                }
    }
    __syncthreads();

    // coalesced v-part store
    for (int i = tid; i < 64 * 96; i += 256) {
        int e = i / 96, c = i - e * 96;
        int ge = e0 + e;
        if (ge < E) out[ge * 160 + 64 + c] = OUTV[e * 100 + c];
    }
}

extern "C" void kernel_launch(void* const* d_in, const int* in_sizes, int n_in,
                              void* d_out, int out_size, void* d_ws, size_t ws_size,
                              hipStream_t stream) {
    const float* fea1  = (const float*)d_in[0];
    const float* fea2  = (const float*)d_in[1];
    const float* wss_s = (const float*)d_in[4];
    const float* wvv_s = (const float*)d_in[5];
    const float* wss_g = (const float*)d_in[6];
    const float* wvv_g = (const float*)d_in[7];
    const float* wsv   = (const float*)d_in[8];
    const float* wvs   = (const float*)d_in[9];
    const float* wls   = (const float*)d_in[10];
    const float* wlv   = (const float*)d_in[11];
    float* out = (float*)d_out;

    f16* b1p  = (f16*)d_ws;                               // 983040 B
    f16* b2p  = (f16*)((char*)d_ws + 983040);             // 262144 B
    f16* wlsP = (f16*)((char*)d_ws + 1245184);            // 8192 B
    f16* wlvP = (f16*)((char*)d_ws + 1253376);            // 2048 B

    int E = in_sizes[0] / 160;   // 100000
    int prep_total = 491520 + 131072 + 4096 + 1024;       // 627712
    prep_weights<<<dim3((prep_total + 255) / 256), dim3(256), 0, stream>>>(
        wss_s, wvv_s, wss_g, wvv_g, wsv, wvs, wls, wlv, b1p, b2p, wlsP, wlvP);
    int grid = (E + 63) / 64;    // 1563
    seconv_mfma<<<dim3(grid), dim3(256), 0, stream>>>(
        fea1, fea2, b1p, b2p, wlsP, wlvP, out, E);
}

// Round 4
// 411.502 us; speedup vs baseline: 1.1064x; 1.1064x over previous
//
#include <hip/hip_runtime.h>

// SelfEquiConv E=100000, S=64, V=32 — f16 MFMA formulation (round 6).
// = round-4 structure (depth-2 B prefetch, 84 VGPR) + round-5's 40960 B swizzled LDS
//   => 4 blocks/CU without the VGPR spill that killed round 5.
// G1: [z_s|z_g], K=5120, N=96, accs in registers through G2.
// G2: z_v rows (i3, e): wave w owns e-strip w*16..+15, FULL K=4096.
// IN layout: [64 rows][320 f16], row stride 640 B, XOR swizzle byte^=(e&7)<<4.

typedef _Float16 f16;
typedef _Float16 f16x8 __attribute__((ext_vector_type(8)));
typedef float    f32x4 __attribute__((ext_vector_type(4)));

constexpr float A_SS  = 0.011048543456039806f; // (2*64*64)^-0.5  == A_SS_G
constexpr float A_VV  = 0.012757759747374832f; // (2*32*32*3)^-0.5 == A_VV_G
constexpr float A_SV  = 0.009021097956087904f; // (2*64*32*3)^-0.5 == A_VS_V
constexpr float SO_SC = 0.125f;                // 64^-0.5
constexpr float VO_SC = 0.1767766952966369f;   // 32^-0.5

#define MFMA16(A, B, C) __builtin_amdgcn_mfma_f32_16x16x32_f16((A), (B), (C), 0, 0, 0)

static __device__ __forceinline__ f16x8 splat8(f16 x) {
    return (f16x8){x, x, x, x, x, x, x, x};
}

// ---------------- prep: swizzle weights into MFMA B-fragment order (f16) ----------------
// b1p:  [160 kchunks][6 t][64 L][8]   k=c*32+(L>>4)*8+j, n=t*16+(L&15)
// b2p:  [128 kchunks][2 t][64 L][8]
// wlsP: [2 kc][4 t][64 L][8]          *SO_SC
// wlvP: [2 t][64 L][8]                *VO_SC
__global__ void prep_weights(const float* __restrict__ wss_s, const float* __restrict__ wvv_s,
                             const float* __restrict__ wss_g, const float* __restrict__ wvv_g,
                             const float* __restrict__ wsv,   const float* __restrict__ wvs,
                             const float* __restrict__ wls,   const float* __restrict__ wlv,
                             f16* __restrict__ b1p, f16* __restrict__ b2p,
                             f16* __restrict__ wlsP, f16* __restrict__ wlvP)
{
    int idx = blockIdx.x * 256 + threadIdx.x;
    const int N1 = 160 * 6 * 512;          // 491520
    const int N2 = 128 * 2 * 512;          // 131072
    const int N3 = 8 * 512;                // 4096
    const int N4 = 2 * 512;                // 1024
    if (idx < N1) {
        int j = idx & 7, L = (idx >> 3) & 63, ct = idx >> 9;
        int t = ct % 6, c = ct / 6;
        int k = c * 32 + (L >> 4) * 8 + j;
        int n = t * 16 + (L & 15);
        float val;
        if (k < 4096) { int u = k >> 6, v = k & 63, p = u * 64 + v;
            val = A_SS * (n < 64 ? wss_s[p * 64 + n] : wss_g[p * 32 + (n - 64)]);
        } else { int k2 = k - 4096; int u = k2 >> 5, v = k2 & 31, p = u * 32 + v;
            val = A_VV * (n < 64 ? wvv_s[p * 64 + n] : wvv_g[p * 32 + (n - 64)]);
        }
        b1p[idx] = (f16)val;
    } else if (idx < N1 + N2) {
        int id2 = idx - N1;
        int j = id2 & 7, L = (id2 >> 3) & 63, ct = id2 >> 9;
        int t = ct & 1, c = ct >> 1;
        int k = c * 32 + (L >> 4) * 8 + j;
        int n = t * 16 + (L & 15);
        float val;
        if (k < 2048) { int u = k >> 5, v = k & 31; val = wsv[(u * 32 + v) * 32 + n]; }
        else { int k2 = k - 2048; int u = k2 >> 6, v = k2 & 63; val = wvs[(u * 64 + v) * 32 + n]; }
        b2p[id2] = (f16)(A_SV * val);
    } else if (idx < N1 + N2 + N3) {
        int id3 = idx - N1 - N2;
        int j = id3 & 7, L = (id3 >> 3) & 63, ct = id3 >> 9;   // ct in [0,8)
        int t = ct & 3, kc = ct >> 2;
        int k = kc * 32 + (L >> 4) * 8 + j;
        int n = t * 16 + (L & 15);
        wlsP[id3] = (f16)(SO_SC * wls[k * 64 + n]);
    } else if (idx < N1 + N2 + N3 + N4) {
        int id4 = idx - N1 - N2 - N3;
        int j = id4 & 7, L = (id4 >> 3) & 63, t = id4 >> 9;    // t in [0,2)
        int k = (L >> 4) * 8 + j;
        int n = t * 16 + (L & 15);
        wlvP[id4] = (f16)(VO_SC * wlv[k * 32 + n]);
    }
}

// ---------------- main kernel: 64 edges/block, 4 waves, 4 blocks/CU ----------------
// smem (40960 B):
//   phase 1: IN swizzled [64][320] f16 (stride 640 B)
//   phase 2 (overlay): zSh f16 [64][72] @0, zGh f16 [64][34] @9216, ZVH f16 [192][40] @13568
//   phase 3: OUTV f32 [64][100] @0 (25600)
__global__ __launch_bounds__(256, 4)
void seconv_mfma(const float* __restrict__ fea1, const float* __restrict__ fea2,
                 const f16* __restrict__ b1p, const f16* __restrict__ b2p,
                 const f16* __restrict__ wlsP, const f16* __restrict__ wlvP,
                 float* __restrict__ out, int E)
{
    __shared__ __align__(128) char smem[40960];
    f16*   zSh  = (f16*)smem;             // overlays, valid after G2 barrier
    f16*   zGh  = (f16*)(smem + 9216);
    f16*   ZVH  = (f16*)(smem + 13568);
    float* OUTV = (float*)smem;

    const int tid  = threadIdx.x;
    const int lane = tid & 63;
    const int m    = lane & 15;
    const int quad = lane >> 4;
    const int w    = tid >> 6;
    const int h    = w & 1;       // G1 edge half
    const int nh   = w >> 1;      // G1 n-half (tiles 3nh..3nh+2)
    const int tb   = nh * 3;
    const int e0   = blockIdx.x * 64;

    // swizzled IN accessors (hc = f16 column index 0..319)
    auto ld8 = [&](int e, int hc) -> f16x8 {
        int b = (e * 640 + hc * 2) ^ ((e & 7) << 4);
        return *(const f16x8*)(smem + b);
    };
    auto st2 = [&](int e, int hc, f16 v) {
        int b = (e * 640 + hc * 2) ^ ((e & 7) << 4);
        *(f16*)(smem + b) = v;
    };

    // ---- stage inputs as f16 (v-parts transposed to [i][v]) ----
    for (int i = tid; i < 64 * 160; i += 256) {
        int e = i / 160, c = i - e * 160;
        int ge = e0 + e; if (ge >= E) ge = E - 1;
        float a = fea1[ge * 160 + c];
        float b = fea2[ge * 160 + c];
        if (c < 64) { st2(e, c, (f16)a); st2(e, 64 + c, (f16)b); }
        else { int c2 = c - 64; int v = c2 / 3, ii = c2 - v * 3;
               st2(e, 128 + ii * 32 + v, (f16)a);
               st2(e, 224 + ii * 32 + v, (f16)b); }
    }
    __syncthreads();

    const int eA = h * 32 + m;        // G1 strip p=0 edge
    const int eB = h * 32 + 16 + m;   // G1 strip p=1 edge

    // G1 fragment preloads
    f16x8 s2q[2][2], v2q[2][3];
    #pragma unroll
    for (int p = 0; p < 2; ++p) {
        int e = p ? eB : eA;
        #pragma unroll
        for (int vh = 0; vh < 2; ++vh)
            s2q[p][vh] = ld8(e, 64 + vh * 32 + quad * 8);
        #pragma unroll
        for (int i3 = 0; i3 < 3; ++i3)
            v2q[p][i3] = ld8(e, 224 + i3 * 32 + quad * 8);
    }

    // ================= G1: [z_s|z_g], 160 kchunks, depth-2 B prefetch =================
    f32x4 acc[2][3];
    #pragma unroll
    for (int p = 0; p < 2; ++p)
        #pragma unroll
        for (int t = 0; t < 3; ++t) acc[p][t] = (f32x4){0.f, 0.f, 0.f, 0.f};

    f32x4 bcur[3], bnxt[3];
    #pragma unroll
    for (int t = 0; t < 3; ++t) bcur[t] = *(const f32x4*)(b1p + ((0 * 6 + tb + t) * 64 + lane) * 8);
    #pragma unroll
    for (int t = 0; t < 3; ++t) bnxt[t] = *(const f32x4*)(b1p + ((1 * 6 + tb + t) * 64 + lane) * 8);

    // P-part: chunks 0..127, c = (ub*8+uj)*2+vh
    for (int ub = 0; ub < 8; ++ub) {
        f16x8 s1Ab = ld8(eA, ub * 8);
        f16x8 s1Bb = ld8(eB, ub * 8);
        #pragma unroll
        for (int uj = 0; uj < 8; ++uj) {
            f16x8 s1A = splat8(s1Ab[uj]);
            f16x8 s1B = splat8(s1Bb[uj]);
            #pragma unroll
            for (int vh = 0; vh < 2; ++vh) {
                int c = (ub * 8 + uj) * 2 + vh;
                f16x8 a0 = s1A * s2q[0][vh];
                f16x8 a1 = s1B * s2q[1][vh];
                f32x4 b0 = bcur[0], b1 = bcur[1], b2 = bcur[2];
                #pragma unroll
                for (int t = 0; t < 3; ++t) bcur[t] = bnxt[t];
                int cn = c + 2;                       // <=129, always valid
                #pragma unroll
                for (int t = 0; t < 3; ++t)
                    bnxt[t] = *(const f32x4*)(b1p + ((cn * 6 + tb + t) * 64 + lane) * 8);
                f16x8 bb0 = __builtin_bit_cast(f16x8, b0);
                f16x8 bb1 = __builtin_bit_cast(f16x8, b1);
                f16x8 bb2 = __builtin_bit_cast(f16x8, b2);
                acc[0][0] = MFMA16(a0, bb0, acc[0][0]);
                acc[0][1] = MFMA16(a0, bb1, acc[0][1]);
                acc[0][2] = MFMA16(a0, bb2, acc[0][2]);
                acc[1][0] = MFMA16(a1, bb0, acc[1][0]);
                acc[1][1] = MFMA16(a1, bb1, acc[1][1]);
                acc[1][2] = MFMA16(a1, bb2, acc[1][2]);
            }
        }
    }
    // Q-part: chunks 128..159
    for (int ub = 0; ub < 4; ++ub) {
        f16x8 xA[3], xB[3];
        #pragma unroll
        for (int i3 = 0; i3 < 3; ++i3) {
            xA[i3] = ld8(eA, 128 + i3 * 32 + ub * 8);
            xB[i3] = ld8(eB, 128 + i3 * 32 + ub * 8);
        }
        #pragma unroll
        for (int uj = 0; uj < 8; ++uj) {
            int c = 128 + ub * 8 + uj;
            f16x8 a0 = splat8(xA[0][uj]) * v2q[0][0];
            a0 += splat8(xA[1][uj]) * v2q[0][1];
            a0 += splat8(xA[2][uj]) * v2q[0][2];
            f16x8 a1 = splat8(xB[0][uj]) * v2q[1][0];
            a1 += splat8(xB[1][uj]) * v2q[1][1];
            a1 += splat8(xB[2][uj]) * v2q[1][2];
            f32x4 b0 = bcur[0], b1 = bcur[1], b2 = bcur[2];
            #pragma unroll
            for (int t = 0; t < 3; ++t) bcur[t] = bnxt[t];
            int cn = c + 2; if (cn > 159) cn = 159;
            #pragma unroll
            for (int t = 0; t < 3; ++t)
                bnxt[t] = *(const f32x4*)(b1p + ((cn * 6 + tb + t) * 64 + lane) * 8);
            f16x8 bb0 = __builtin_bit_cast(f16x8, b0);
            f16x8 bb1 = __builtin_bit_cast(f16x8, b1);
            f16x8 bb2 = __builtin_bit_cast(f16x8, b2);
            acc[0][0] = MFMA16(a0, bb0, acc[0][0]);
            acc[0][1] = MFMA16(a0, bb1, acc[0][1]);
            acc[0][2] = MFMA16(a0, bb2, acc[0][2]);
            acc[1][0] = MFMA16(a1, bb0, acc[1][0]);
            acc[1][1] = MFMA16(a1, bb1, acc[1][1]);
            acc[1][2] = MFMA16(a1, bb2, acc[1][2]);
        }
    }

    // ================= G2: z_v, wave w owns rows (i3, e2=w*16+m), FULL K =================
    const int e2 = w * 16 + m;
    f16x8 s2g[2], v2g[3];
    #pragma unroll
    for (int vh = 0; vh < 2; ++vh)
        s2g[vh] = ld8(e2, 64 + vh * 32 + quad * 8);
    #pragma unroll
    for (int i3 = 0; i3 < 3; ++i3)
        v2g[i3] = ld8(e2, 224 + i3 * 32 + quad * 8);

    f32x4 acc2[3][2];
    #pragma unroll
    for (int i3 = 0; i3 < 3; ++i3)
        #pragma unroll
        for (int t = 0; t < 2; ++t) acc2[i3][t] = (f32x4){0.f, 0.f, 0.f, 0.f};

    f32x4 q0 = *(const f32x4*)(b2p + ((0 * 2 + 0) * 64 + lane) * 8);
    f32x4 q1 = *(const f32x4*)(b2p + ((0 * 2 + 1) * 64 + lane) * 8);
    f32x4 r0 = *(const f32x4*)(b2p + ((1 * 2 + 0) * 64 + lane) * 8);
    f32x4 r1 = *(const f32x4*)(b2p + ((1 * 2 + 1) * 64 + lane) * 8);

    // sv phase: chunk c = ub*8+uj
    for (int ub = 0; ub < 8; ++ub) {
        f16x8 s1b = ld8(e2, ub * 8);
        #pragma unroll
        for (int uj = 0; uj < 8; ++uj) {
            int c = ub * 8 + uj;
            f16x8 bb0 = __builtin_bit_cast(f16x8, q0);
            f16x8 bb1 = __builtin_bit_cast(f16x8, q1);
            q0 = r0; q1 = r1;
            int cn = c + 2;                            // <=65, valid
            r0 = *(const f32x4*)(b2p + ((cn * 2 + 0) * 64 + lane) * 8);
            r1 = *(const f32x4*)(b2p + ((cn * 2 + 1) * 64 + lane) * 8);
            f16x8 sxv = splat8(s1b[uj]);
            #pragma unroll
            for (int i3 = 0; i3 < 3; ++i3) {
                f16x8 a = sxv * v2g[i3];
                acc2[i3][0] = MFMA16(a, bb0, acc2[i3][0]);
                acc2[i3][1] = MFMA16(a, bb1, acc2[i3][1]);
            }
        }
    }
    // vs phase: chunk c = 64 + (ub*8+uj)*2 + vh
    for (int ub = 0; ub < 4; ++ub) {
        f16x8 v1b[3];
        #pragma unroll
        for (int i3 = 0; i3 < 3; ++i3)
            v1b[i3] = ld8(e2, 128 + i3 * 32 + ub * 8);
        #pragma unroll
        for (int uj = 0; uj < 8; ++uj) {
            f16x8 v1s0 = splat8(v1b[0][uj]);
            f16x8 v1s1 = splat8(v1b[1][uj]);
            f16x8 v1s2 = splat8(v1b[2][uj]);
            #pragma unroll
            for (int vh = 0; vh < 2; ++vh) {
                int c = 64 + (ub * 8 + uj) * 2 + vh;
                f16x8 bb0 = __builtin_bit_cast(f16x8, q0);
                f16x8 bb1 = __builtin_bit_cast(f16x8, q1);
                q0 = r0; q1 = r1;
                int cn = c + 2; if (cn > 127) cn = 127;
                r0 = *(const f32x4*)(b2p + ((cn * 2 + 0) * 64 + lane) * 8);
                r1 = *(const f32x4*)(b2p + ((cn * 2 + 1) * 64 + lane) * 8);
                f16x8 a0 = v1s0 * s2g[vh];
                f16x8 a1 = v1s1 * s2g[vh];
                f16x8 a2 = v1s2 * s2g[vh];
                acc2[0][0] = MFMA16(a0, bb0, acc2[0][0]);
                acc2[0][1] = MFMA16(a0, bb1, acc2[0][1]);
                acc2[1][0] = MFMA16(a1, bb0, acc2[1][0]);
                acc2[1][1] = MFMA16(a1, bb1, acc2[1][1]);
                acc2[2][0] = MFMA16(a2, bb0, acc2[2][0]);
                acc2[2][1] = MFMA16(a2, bb1, acc2[2][1]);
            }
        }
    }
    __syncthreads();   // all IN reads done — overlays become legal

    // ---- z write: silu(zS) and raw zG to LDS (overlay IN) ----
    #pragma unroll
    for (int p = 0; p < 2; ++p)
        #pragma unroll
        for (int t = 0; t < 3; ++t) {
            int n = (tb + t) * 16 + m;
            #pragma unroll
            for (int r = 0; r < 4; ++r) {
                int e_loc = h * 32 + p * 16 + quad * 4 + r;
                float z = acc[p][t][r];
                if (n < 64) {
                    float s = z / (1.f + __expf(-z));
                    zSh[e_loc * 72 + n] = (f16)s;
                } else {
                    zGh[e_loc * 34 + (n - 64)] = (f16)z;
                }
            }
        }
    __syncthreads();

    // ---- gate + ZVH write (wave w writes its own e-strip rows) ----
    #pragma unroll
    for (int t = 0; t < 2; ++t)
        #pragma unroll
        for (int r = 0; r < 4; ++r) {
            int e_loc = w * 16 + quad * 4 + r;
            float zg = (float)zGh[e_loc * 34 + t * 16 + m];
            float gate = 1.f / (1.f + __expf(-zg));
            #pragma unroll
            for (int i3 = 0; i3 < 3; ++i3)
                ZVH[(i3 * 64 + e_loc) * 40 + t * 16 + m] = (f16)(gate * acc2[i3][t][r]);
        }

    // ================= epilogue GEMMs (f16 MFMA) =================
    // GEMM-S: out_s = silu(zS) @ wlsP ; wave w owns m-strip w, 4 n-tiles
    {
        f32x4 accS[4];
        #pragma unroll
        for (int t = 0; t < 4; ++t) accS[t] = (f32x4){0.f, 0.f, 0.f, 0.f};
        #pragma unroll
        for (int kc = 0; kc < 2; ++kc) {
            f16x8 aS = *(const f16x8*)(zSh + (w * 16 + m) * 72 + kc * 32 + quad * 8);
            #pragma unroll
            for (int t = 0; t < 4; ++t) {
                f32x4 braw = *(const f32x4*)(wlsP + ((kc * 4 + t) * 64 + lane) * 8);
                accS[t] = MFMA16(aS, __builtin_bit_cast(f16x8, braw), accS[t]);
            }
        }
        #pragma unroll
        for (int t = 0; t < 4; ++t)
            #pragma unroll
            for (int r = 0; r < 4; ++r) {
                int ge = e0 + w * 16 + quad * 4 + r;
                if (ge < E) out[ge * 160 + t * 16 + m] = accS[t][r];
            }
    }
    // GEMM-V: rows (i3, e-strip w) = gated z_v @ wlvP (own-wave ZVH rows)
    {
        f32x4 accV[3][2];
        #pragma unroll
        for (int i3 = 0; i3 < 3; ++i3)
            #pragma unroll
            for (int t = 0; t < 2; ++t) accV[i3][t] = (f32x4){0.f, 0.f, 0.f, 0.f};
        f16x8 bV[2];
        #pragma unroll
        for (int t = 0; t < 2; ++t) {
            f32x4 braw = *(const f32x4*)(wlvP + (t * 64 + lane) * 8);
            bV[t] = __builtin_bit_cast(f16x8, braw);
        }
        #pragma unroll
        for (int i3 = 0; i3 < 3; ++i3) {
            f16x8 aV = *(const f16x8*)(ZVH + (i3 * 64 + w * 16 + m) * 40 + quad * 8);
            #pragma unroll
            for (int t = 0; t < 2; ++t) accV[i3][t] = MFMA16(aV, bV[t], accV[i3][t]);
        }
        __syncthreads();   // all zSh/ZVH reads done — OUTV overlay safe
        #pragma unroll
        for (int i3 = 0; i3 < 3; ++i3)
            #pragma unroll
            for (int t = 0; t < 2; ++t)
                #pragma unroll
                for (int r = 0; r < 4; ++r) {
                    int e_loc = w * 16 + quad * 4 + r;
                    OUTV[e_loc * 100 + (t * 16 + m) * 3 + i3] = accV[i3][t][r];
                }
    }
    __syncthreads();

    // coalesced v-part store
    for (int i = tid; i < 64 * 96; i += 256) {
        int e = i / 96, c = i - e * 96;
        int ge = e0 + e;
        if (ge < E) out[ge * 160 + 64 + c] = OUTV[e * 100 + c];
    }
}

extern "C" void kernel_launch(void* const* d_in, const int* in_sizes, int n_in,
                              void* d_out, int out_size, void* d_ws, size_t ws_size,
                              hipStream_t stream) {
    const float* fea1  = (const float*)d_in[0];
    const float* fea2  = (const float*)d_in[1];
    const float* wss_s = (const float*)d_in[4];
    const float* wvv_s = (const float*)d_in[5];
    const float* wss_g = (const float*)d_in[6];
    const float* wvv_g = (const float*)d_in[7];
    const float* wsv   = (const float*)d_in[8];
    const float* wvs   = (const float*)d_in[9];
    const float* wls   = (const float*)d_in[10];
    const float* wlv   = (const float*)d_in[11];
    float* out = (float*)d_out;

    f16* b1p  = (f16*)d_ws;                               // 983040 B
    f16* b2p  = (f16*)((char*)d_ws + 983040);             // 262144 B
    f16* wlsP = (f16*)((char*)d_ws + 1245184);            // 8192 B
    f16* wlvP = (f16*)((char*)d_ws + 1253376);            // 2048 B

    int E = in_sizes[0] / 160;   // 100000
    int prep_total = 491520 + 131072 + 4096 + 1024;       // 627712
    prep_weights<<<dim3((prep_total + 255) / 256), dim3(256), 0, stream>>>(
        wss_s, wvv_s, wss_g, wvv_g, wsv, wvs, wls, wlv, b1p, b2p, wlsP, wlvP);
    int grid = (E + 63) / 64;    // 1563
    seconv_mfma<<<dim3(grid), dim3(256), 0, stream>>>(
        fea1, fea2, b1p, b2p, wlsP, wlvP, out, E);
}

// Round 5
// 396.719 us; speedup vs baseline: 1.1477x; 1.0373x over previous
//
#include <hip/hip_runtime.h>

// SelfEquiConv E=100000, S=64, V=32 — f16 MFMA formulation (round 7).
// vs r6: (a) b1p re-laid out per-nh sequential: [nh][160 c][3 t][512]; SGPR base
//            (readfirstlane) + linear pointer walk + imm offsets — cuts addr VALU.
//        (b) static-parity 2-slot B rings (bq[c&1]) — no register rotation moves.
//        (c) G1 acc packed to f16 (silu early) before G2 — 24->12 regs live in G2.
//        (d) v2q preload moved to Q-part; Q x-batches f16x4 — lower VGPR peaks,
//            kill the ~17MB residual scratch spill seen in r6.

typedef _Float16 f16;
typedef _Float16 f16x4 __attribute__((ext_vector_type(4)));
typedef _Float16 f16x8 __attribute__((ext_vector_type(8)));
typedef float    f32x4 __attribute__((ext_vector_type(4)));

constexpr float A_SS  = 0.011048543456039806f; // (2*64*64)^-0.5  == A_SS_G
constexpr float A_VV  = 0.012757759747374832f; // (2*32*32*3)^-0.5 == A_VV_G
constexpr float A_SV  = 0.009021097956087904f; // (2*64*32*3)^-0.5 == A_VS_V
constexpr float SO_SC = 0.125f;                // 64^-0.5
constexpr float VO_SC = 0.1767766952966369f;   // 32^-0.5

#define MFMA16(A, B, C) __builtin_amdgcn_mfma_f32_16x16x32_f16((A), (B), (C), 0, 0, 0)

static __device__ __forceinline__ f16x8 splat8(f16 x) {
    return (f16x8){x, x, x, x, x, x, x, x};
}

// ---------------- prep: swizzle weights into MFMA B-fragment order (f16) ----------------
// b1p:  [2 nh][160 c][3 t][64 L][8]  k=c*32+(L>>4)*8+j, n=(nh*3+t)*16+(L&15)  (per-nh stream)
// b2p:  [128 c][2 t][64 L][8]        (already sequential per wave stream)
// wlsP: [2 kc][4 t][64 L][8]         *SO_SC
// wlvP: [2 t][64 L][8]               *VO_SC
__global__ void prep_weights(const float* __restrict__ wss_s, const float* __restrict__ wvv_s,
                             const float* __restrict__ wss_g, const float* __restrict__ wvv_g,
                             const float* __restrict__ wsv,   const float* __restrict__ wvs,
                             const float* __restrict__ wls,   const float* __restrict__ wlv,
                             f16* __restrict__ b1p, f16* __restrict__ b2p,
                             f16* __restrict__ wlsP, f16* __restrict__ wlvP)
{
    int idx = blockIdx.x * 256 + threadIdx.x;
    const int N1 = 2 * 160 * 3 * 512;      // 491520
    const int N2 = 128 * 2 * 512;          // 131072
    const int N3 = 8 * 512;                // 4096
    const int N4 = 2 * 512;                // 1024
    if (idx < N1) {
        int j = idx & 7, L = (idx >> 3) & 63, rest = idx >> 9;  // rest in [0,960)
        int t3 = rest % 3, rc = rest / 3;                        // rc in [0,320)
        int c = rc % 160, nh2 = rc / 160;
        int k = c * 32 + (L >> 4) * 8 + j;
        int n = (nh2 * 3 + t3) * 16 + (L & 15);
        float val;
        if (k < 4096) { int u = k >> 6, v = k & 63, p = u * 64 + v;
            val = A_SS * (n < 64 ? wss_s[p * 64 + n] : wss_g[p * 32 + (n - 64)]);
        } else { int k2 = k - 4096; int u = k2 >> 5, v = k2 & 31, p = u * 32 + v;
            val = A_VV * (n < 64 ? wvv_s[p * 64 + n] : wvv_g[p * 32 + (n - 64)]);
        }
        b1p[idx] = (f16)val;
    } else if (idx < N1 + N2) {
        int id2 = idx - N1;
        int j = id2 & 7, L = (id2 >> 3) & 63, ct = id2 >> 9;
        int t = ct & 1, c = ct >> 1;
        int k = c * 32 + (L >> 4) * 8 + j;
        int n = t * 16 + (L & 15);
        float val;
        if (k < 2048) { int u = k >> 5, v = k & 31; val = wsv[(u * 32 + v) * 32 + n]; }
        else { int k2 = k - 2048; int u = k2 >> 6, v = k2 & 63; val = wvs[(u * 64 + v) * 32 + n]; }
        b2p[id2] = (f16)(A_SV * val);
    } else if (idx < N1 + N2 + N3) {
        int id3 = idx - N1 - N2;
        int j = id3 & 7, L = (id3 >> 3) & 63, ct = id3 >> 9;   // ct in [0,8)
        int t = ct & 3, kc = ct >> 2;
        int k = kc * 32 + (L >> 4) * 8 + j;
        int n = t * 16 + (L & 15);
        wlsP[id3] = (f16)(SO_SC * wls[k * 64 + n]);
    } else if (idx < N1 + N2 + N3 + N4) {
        int id4 = idx - N1 - N2 - N3;
        int j = id4 & 7, L = (id4 >> 3) & 63, t = id4 >> 9;    // t in [0,2)
        int k = (L >> 4) * 8 + j;
        int n = t * 16 + (L & 15);
        wlvP[id4] = (f16)(VO_SC * wlv[k * 32 + n]);
    }
}

// ---------------- main kernel: 64 edges/block, 4 waves, 4 blocks/CU ----------------
// smem (40960 B):
//   phase 1: IN swizzled [64][320] f16 (stride 640 B), byte^=(e&7)<<4
//   phase 2 (overlay): zSh f16 [64][72] @0, zGh f16 [64][34] @9216, ZVH f16 [192][40] @13568
//   phase 3: OUTV f32 [64][100] @0 (25600)
__global__ __launch_bounds__(256, 4)
void seconv_mfma(const float* __restrict__ fea1, const float* __restrict__ fea2,
                 const f16* __restrict__ b1p, const f16* __restrict__ b2p,
                 const f16* __restrict__ wlsP, const f16* __restrict__ wlvP,
                 float* __restrict__ out, int E)
{
    __shared__ __align__(128) char smem[40960];
    f16*   zSh  = (f16*)smem;             // overlays, valid after G2 barrier
    f16*   zGh  = (f16*)(smem + 9216);
    f16*   ZVH  = (f16*)(smem + 13568);
    float* OUTV = (float*)smem;

    const int tid  = threadIdx.x;
    const int lane = tid & 63;
    const int m    = lane & 15;
    const int quad = lane >> 4;
    const int w    = tid >> 6;
    const int h    = w & 1;       // G1 edge half
    const int nh   = w >> 1;      // G1 n-half (tiles 3nh..3nh+2)
    const int tb   = nh * 3;
    const int e0   = blockIdx.x * 64;

    // swizzled IN accessors (hc = f16 column index 0..319)
    auto ld8 = [&](int e, int hc) -> f16x8 {
        int b = (e * 640 + hc * 2) ^ ((e & 7) << 4);
        return *(const f16x8*)(smem + b);
    };
    auto ld4 = [&](int e, int hc) -> f16x4 {
        int b = (e * 640 + hc * 2) ^ ((e & 7) << 4);
        return *(const f16x4*)(smem + b);
    };
    auto st2 = [&](int e, int hc, f16 v) {
        int b = (e * 640 + hc * 2) ^ ((e & 7) << 4);
        *(f16*)(smem + b) = v;
    };

    // ---- stage inputs as f16 (v-parts transposed to [i][v]) ----
    for (int i = tid; i < 64 * 160; i += 256) {
        int e = i / 160, c = i - e * 160;
        int ge = e0 + e; if (ge >= E) ge = E - 1;
        float a = fea1[ge * 160 + c];
        float b = fea2[ge * 160 + c];
        if (c < 64) { st2(e, c, (f16)a); st2(e, 64 + c, (f16)b); }
        else { int c2 = c - 64; int v = c2 / 3, ii = c2 - v * 3;
               st2(e, 128 + ii * 32 + v, (f16)a);
               st2(e, 224 + ii * 32 + v, (f16)b); }
    }
    __syncthreads();

    const int eA = h * 32 + m;        // G1 strip p=0 edge
    const int eB = h * 32 + 16 + m;   // G1 strip p=1 edge

    // ================= G1: [z_s|z_g], 160 kchunks, static-parity 2-slot ring =================
    f32x4 acc[2][3];
    #pragma unroll
    for (int p = 0; p < 2; ++p)
        #pragma unroll
        for (int t = 0; t < 3; ++t) acc[p][t] = (f32x4){0.f, 0.f, 0.f, 0.f};

    // wave's sequential B stream (SGPR base via readfirstlane)
    const f16* pB = b1p + __builtin_amdgcn_readfirstlane(nh) * (160 * 3 * 512);
    f32x4 bq[2][3];                   // slot = chunk parity
    #pragma unroll
    for (int t = 0; t < 3; ++t) bq[0][t] = *(const f32x4*)(pB + t * 512 + lane * 8);
    pB += 1536;
    #pragma unroll
    for (int t = 0; t < 3; ++t) bq[1][t] = *(const f32x4*)(pB + t * 512 + lane * 8);
    pB += 1536;   // -> chunk 2

    // P-part: chunks 0..127, c = (ub*8+uj)*2+vh, parity = vh
    {
        f16x8 s2q[2][2];
        #pragma unroll
        for (int p = 0; p < 2; ++p)
            #pragma unroll
            for (int vh = 0; vh < 2; ++vh)
                s2q[p][vh] = ld8(p ? eB : eA, 64 + vh * 32 + quad * 8);

        for (int ub = 0; ub < 8; ++ub) {
            f16x8 s1Ab = ld8(eA, ub * 8);
            f16x8 s1Bb = ld8(eB, ub * 8);
            #pragma unroll
            for (int uj = 0; uj < 8; ++uj) {
                f16x8 s1A = splat8(s1Ab[uj]);
                f16x8 s1B = splat8(s1Bb[uj]);
                #pragma unroll
                for (int vh = 0; vh < 2; ++vh) {
                    f16x8 bb0 = __builtin_bit_cast(f16x8, bq[vh][0]);
                    f16x8 bb1 = __builtin_bit_cast(f16x8, bq[vh][1]);
                    f16x8 bb2 = __builtin_bit_cast(f16x8, bq[vh][2]);
                    #pragma unroll
                    for (int t = 0; t < 3; ++t)
                        bq[vh][t] = *(const f32x4*)(pB + t * 512 + lane * 8);
                    pB += 1536;   // over-prefetch past chunk 159 lands in b2p, never consumed
                    f16x8 a0 = s1A * s2q[0][vh];
                    f16x8 a1 = s1B * s2q[1][vh];
                    acc[0][0] = MFMA16(a0, bb0, acc[0][0]);
                    acc[0][1] = MFMA16(a0, bb1, acc[0][1]);
                    acc[0][2] = MFMA16(a0, bb2, acc[0][2]);
                    acc[1][0] = MFMA16(a1, bb0, acc[1][0]);
                    acc[1][1] = MFMA16(a1, bb1, acc[1][1]);
                    acc[1][2] = MFMA16(a1, bb2, acc[1][2]);
                }
            }
        }
    }
    // Q-part: chunks 128..159, c = 128 + ub*4 + uj, parity = uj&1
    {
        f16x8 v2q[2][3];
        #pragma unroll
        for (int p = 0; p < 2; ++p)
            #pragma unroll
            for (int i3 = 0; i3 < 3; ++i3)
                v2q[p][i3] = ld8(p ? eB : eA, 224 + i3 * 32 + quad * 8);

        for (int ub = 0; ub < 8; ++ub) {
            f16x4 xA[3], xB[3];
            #pragma unroll
            for (int i3 = 0; i3 < 3; ++i3) {
                xA[i3] = ld4(eA, 128 + i3 * 32 + ub * 4);
                xB[i3] = ld4(eB, 128 + i3 * 32 + ub * 4);
            }
            #pragma unroll
            for (int uj = 0; uj < 4; ++uj) {
                const int slot = uj & 1;
                f16x8 bb0 = __builtin_bit_cast(f16x8, bq[slot][0]);
                f16x8 bb1 = __builtin_bit_cast(f16x8, bq[slot][1]);
                f16x8 bb2 = __builtin_bit_cast(f16x8, bq[slot][2]);
                #pragma unroll
                for (int t = 0; t < 3; ++t)
                    bq[slot][t] = *(const f32x4*)(pB + t * 512 + lane * 8);
                pB += 1536;
                f16x8 a0 = splat8(xA[0][uj]) * v2q[0][0];
                a0 += splat8(xA[1][uj]) * v2q[0][1];
                a0 += splat8(xA[2][uj]) * v2q[0][2];
                f16x8 a1 = splat8(xB[0][uj]) * v2q[1][0];
                a1 += splat8(xB[1][uj]) * v2q[1][1];
                a1 += splat8(xB[2][uj]) * v2q[1][2];
                acc[0][0] = MFMA16(a0, bb0, acc[0][0]);
                acc[0][1] = MFMA16(a0, bb1, acc[0][1]);
                acc[0][2] = MFMA16(a0, bb2, acc[0][2]);
                acc[1][0] = MFMA16(a1, bb0, acc[1][0]);
                acc[1][1] = MFMA16(a1, bb1, acc[1][1]);
                acc[1][2] = MFMA16(a1, bb2, acc[1][2]);
            }
        }
    }

    // ---- pack G1 accs to f16 NOW (silu applied early) — frees 12 VGPRs across G2 ----
    f16x4 zpk[2][3];
    #pragma unroll
    for (int p = 0; p < 2; ++p)
        #pragma unroll
        for (int t = 0; t < 3; ++t) {
            int n = (tb + t) * 16 + m;
            #pragma unroll
            for (int r = 0; r < 4; ++r) {
                float z = acc[p][t][r];
                float vv = (n < 64) ? (z / (1.f + __expf(-z))) : z;
                zpk[p][t][r] = (f16)vv;
            }
        }

    // ================= G2: z_v, wave w owns rows (i3, e2=w*16+m), FULL K =================
    const int e2 = w * 16 + m;
    f16x8 s2g[2], v2g[3];
    #pragma unroll
    for (int vh = 0; vh < 2; ++vh)
        s2g[vh] = ld8(e2, 64 + vh * 32 + quad * 8);
    #pragma unroll
    for (int i3 = 0; i3 < 3; ++i3)
        v2g[i3] = ld8(e2, 224 + i3 * 32 + quad * 8);

    f32x4 acc2[3][2];
    #pragma unroll
    for (int i3 = 0; i3 < 3; ++i3)
        #pragma unroll
        for (int t = 0; t < 2; ++t) acc2[i3][t] = (f32x4){0.f, 0.f, 0.f, 0.f};

    const f16* pB2 = b2p;             // uniform base, all waves stream chunks 0..127
    f32x4 bq2[2][2];                  // slot = chunk parity
    #pragma unroll
    for (int t = 0; t < 2; ++t) bq2[0][t] = *(const f32x4*)(pB2 + t * 512 + lane * 8);
    pB2 += 1024;
    #pragma unroll
    for (int t = 0; t < 2; ++t) bq2[1][t] = *(const f32x4*)(pB2 + t * 512 + lane * 8);
    pB2 += 1024;  // -> chunk 2

    // sv phase: chunk c = ub*8+uj, parity = uj&1
    for (int ub = 0; ub < 8; ++ub) {
        f16x8 s1b = ld8(e2, ub * 8);
        #pragma unroll
        for (int uj = 0; uj < 8; ++uj) {
            const int slot = uj & 1;
            f16x8 bb0 = __builtin_bit_cast(f16x8, bq2[slot][0]);
            f16x8 bb1 = __builtin_bit_cast(f16x8, bq2[slot][1]);
            #pragma unroll
            for (int t = 0; t < 2; ++t)
                bq2[slot][t] = *(const f32x4*)(pB2 + t * 512 + lane * 8);
            pB2 += 1024;
            f16x8 sxv = splat8(s1b[uj]);
            #pragma unroll
            for (int i3 = 0; i3 < 3; ++i3) {
                f16x8 a = sxv * v2g[i3];
                acc2[i3][0] = MFMA16(a, bb0, acc2[i3][0]);
                acc2[i3][1] = MFMA16(a, bb1, acc2[i3][1]);
            }
        }
    }
    // vs phase: chunk c = 64 + (ub*8+uj)*2 + vh, parity = vh
    for (int ub = 0; ub < 4; ++ub) {
        f16x8 v1b[3];
        #pragma unroll
        for (int i3 = 0; i3 < 3; ++i3)
            v1b[i3] = ld8(e2, 128 + i3 * 32 + ub * 8);
        #pragma unroll
        for (int uj = 0; uj < 8; ++uj) {
            f16x8 v1s0 = splat8(v1b[0][uj]);
            f16x8 v1s1 = splat8(v1b[1][uj]);
            f16x8 v1s2 = splat8(v1b[2][uj]);
            #pragma unroll
            for (int vh = 0; vh < 2; ++vh) {
                const int slot = vh;
                f16x8 bb0 = __builtin_bit_cast(f16x8, bq2[slot][0]);
                f16x8 bb1 = __builtin_bit_cast(f16x8, bq2[slot][1]);
                #pragma unroll
                for (int t = 0; t < 2; ++t)
                    bq2[slot][t] = *(const f32x4*)(pB2 + t * 512 + lane * 8);
                pB2 += 1024;   // over-prefetch past chunk 127 lands in wlsP, never consumed
                f16x8 a0 = v1s0 * s2g[vh];
                f16x8 a1 = v1s1 * s2g[vh];
                f16x8 a2 = v1s2 * s2g[vh];
                acc2[0][0] = MFMA16(a0, bb0, acc2[0][0]);
                acc2[0][1] = MFMA16(a0, bb1, acc2[0][1]);
                acc2[1][0] = MFMA16(a1, bb0, acc2[1][0]);
                acc2[1][1] = MFMA16(a1, bb1, acc2[1][1]);
                acc2[2][0] = MFMA16(a2, bb0, acc2[2][0]);
                acc2[2][1] = MFMA16(a2, bb1, acc2[2][1]);
            }
        }
    }
    __syncthreads();   // all IN reads done — overlays become legal

    // ---- z write: pre-packed f16 (zS already silu'd) to LDS ----
    #pragma unroll
    for (int p = 0; p < 2; ++p)
        #pragma unroll
        for (int t = 0; t < 3; ++t) {
            int n = (tb + t) * 16 + m;
            #pragma unroll
            for (int r = 0; r < 4; ++r) {
                int e_loc = h * 32 + p * 16 + quad * 4 + r;
                if (n < 64) zSh[e_loc * 72 + n] = zpk[p][t][r];
                else        zGh[e_loc * 34 + (n - 64)] = zpk[p][t][r];
            }
        }
    __syncthreads();

    // ---- gate + ZVH write (wave w writes its own e-strip rows) ----
    #pragma unroll
    for (int t = 0; t < 2; ++t)
        #pragma unroll
        for (int r = 0; r < 4; ++r) {
            int e_loc = w * 16 + quad * 4 + r;
            float zg = (float)zGh[e_loc * 34 + t * 16 + m];
            float gate = 1.f / (1.f + __expf(-zg));
            #pragma unroll
            for (int i3 = 0; i3 < 3; ++i3)
                ZVH[(i3 * 64 + e_loc) * 40 + t * 16 + m] = (f16)(gate * acc2[i3][t][r]);
        }

    // ================= epilogue GEMMs (f16 MFMA) =================
    // GEMM-S: out_s = silu(zS) @ wlsP ; wave w owns m-strip w, 4 n-tiles
    {
        f32x4 accS[4];
        #pragma unroll
        for (int t = 0; t < 4; ++t) accS[t] = (f32x4){0.f, 0.f, 0.f, 0.f};
        #pragma unroll
        for (int kc = 0; kc < 2; ++kc) {
            f16x8 aS = *(const f16x8*)(zSh + (w * 16 + m) * 72 + kc * 32 + quad * 8);
            #pragma unroll
            for (int t = 0; t < 4; ++t) {
                f32x4 braw = *(const f32x4*)(wlsP + ((kc * 4 + t) * 64 + lane) * 8);
                accS[t] = MFMA16(aS, __builtin_bit_cast(f16x8, braw), accS[t]);
            }
        }
        #pragma unroll
        for (int t = 0; t < 4; ++t)
            #pragma unroll
            for (int r = 0; r < 4; ++r) {
                int ge = e0 + w * 16 + quad * 4 + r;
                if (ge < E) out[ge * 160 + t * 16 + m] = accS[t][r];
            }
    }
    // GEMM-V: rows (i3, e-strip w) = gated z_v @ wlvP (own-wave ZVH rows)
    {
        f32x4 accV[3][2];
        #pragma unroll
        for (int i3 = 0; i3 < 3; ++i3)
            #pragma unroll
            for (int t = 0; t < 2; ++t) accV[i3][t] = (f32x4){0.f, 0.f, 0.f, 0.f};
        f16x8 bV[2];
        #pragma unroll
        for (int t = 0; t < 2; ++t) {
            f32x4 braw = *(const f32x4*)(wlvP + (t * 64 + lane) * 8);
            bV[t] = __builtin_bit_cast(f16x8, braw);
        }
        #pragma unroll
        for (int i3 = 0; i3 < 3; ++i3) {
            f16x8 aV = *(const f16x8*)(ZVH + (i3 * 64 + w * 16 + m) * 40 + quad * 8);
            #pragma unroll
            for (int t = 0; t < 2; ++t) accV[i3][t] = MFMA16(aV, bV[t], accV[i3][t]);
        }
        __syncthreads();   // all zSh/ZVH reads done — OUTV overlay safe
        #pragma unroll
        for (int i3 = 0; i3 < 3; ++i3)
            #pragma unroll
            for (int t = 0; t < 2; ++t)
                #pragma unroll
                for (int r = 0; r < 4; ++r) {
                    int e_loc = w * 16 + quad * 4 + r;
                    OUTV[e_loc * 100 + (t * 16 + m) * 3 + i3] = accV[i3][t][r];
                }
    }
    __syncthreads();

    // coalesced v-part store
    for (int i = tid; i < 64 * 96; i += 256) {
        int e = i / 96, c = i - e * 96;
        int ge = e0 + e;
        if (ge < E) out[ge * 160 + 64 + c] = OUTV[e * 100 + c];
    }
}

extern "C" void kernel_launch(void* const* d_in, const int* in_sizes, int n_in,
                              void* d_out, int out_size, void* d_ws, size_t ws_size,
                              hipStream_t stream) {
    const float* fea1  = (const float*)d_in[0];
    const float* fea2  = (const float*)d_in[1];
    const float* wss_s = (const float*)d_in[4];
    const float* wvv_s = (const float*)d_in[5];
    const float* wss_g = (const float*)d_in[6];
    const float* wvv_g = (const float*)d_in[7];
    const float* wsv   = (const float*)d_in[8];
    const float* wvs   = (const float*)d_in[9];
    const float* wls   = (const float*)d_in[10];
    const float* wlv   = (const float*)d_in[11];
    float* out = (float*)d_out;

    f16* b1p  = (f16*)d_ws;                               // 983040 B
    f16* b2p  = (f16*)((char*)d_ws + 983040);             // 262144 B
    f16* wlsP = (f16*)((char*)d_ws + 1245184);            // 8192 B
    f16* wlvP = (f16*)((char*)d_ws + 1253376);            // 2048 B

    int E = in_sizes[0] / 160;   // 100000
    int prep_total = 491520 + 131072 + 4096 + 1024;       // 627712
    prep_weights<<<dim3((prep_total + 255) / 256), dim3(256), 0, stream>>>(
        wss_s, wvv_s, wss_g, wvv_g, wsv, wvs, wls, wlv, b1p, b2p, wlsP, wlvP);
    int grid = (E + 63) / 64;    // 1563
    seconv_mfma<<<dim3(grid), dim3(256), 0, stream>>>(
        fea1, fea2, b1p, b2p, wlsP, wlvP, out, E);
}